// Round 1
// baseline (696.505 us; speedup 1.0000x reference)
//
#include <hip/hip_runtime.h>

#define NN 100000
#define NE 220000
#define HD 128
#define NG 4096
#define NPE 5

// x[n][f] = embed[tok[n]][f] + bt[f] + sum_k pe[n][k]*Wt[k][f]
__global__ void k_compute_x(const int* __restrict__ tok,
                            const float* __restrict__ pe,
                            const float* __restrict__ embed,
                            const float* __restrict__ Wt,
                            const float* __restrict__ bt,
                            float* __restrict__ x) {
    int idx = blockIdx.x * blockDim.x + threadIdx.x;
    if (idx >= NN * HD) return;
    int n = idx >> 7, f = idx & 127;
    float acc = embed[tok[n] * HD + f] + bt[f];
    const float* pen = pe + n * NPE;
#pragma unroll
    for (int k = 0; k < NPE; ++k) acc += pen[k] * Wt[k * HD + f];
    x[idx] = acc;
}

__global__ void k_deg(const int* __restrict__ dst, float* __restrict__ deg) {
    int e = blockIdx.x * blockDim.x + threadIdx.x;
    if (e < NE) atomicAdd(&deg[dst[e]], 1.0f);
}

__global__ void k_dinv(float* __restrict__ deg) {
    int n = blockIdx.x * blockDim.x + threadIdx.x;
    if (n < NN) deg[n] = rsqrtf(deg[n] + 1.0f);
}

// h = x @ W, W is [128][128] row-major. Block: 128 threads (f), 32 nodes.
__global__ void k_gemm128(const float* __restrict__ x, const float* __restrict__ W,
                          float* __restrict__ h) {
    __shared__ float xs[32][HD];
    int f = threadIdx.x;
    int n0 = blockIdx.x * 32;
#pragma unroll
    for (int i = 0; i < 32; ++i) {
        int n = n0 + i;
        xs[i][f] = (n < NN) ? x[(size_t)n * HD + f] : 0.0f;
    }
    __syncthreads();
    for (int i = 0; i < 32; i += 4) {
        float a0 = 0.f, a1 = 0.f, a2 = 0.f, a3 = 0.f;
#pragma unroll 8
        for (int k = 0; k < HD; ++k) {
            float w = W[k * HD + f];
            a0 += xs[i + 0][k] * w;
            a1 += xs[i + 1][k] * w;
            a2 += xs[i + 2][k] * w;
            a3 += xs[i + 3][k] * w;
        }
        int n = n0 + i;
        if (n + 0 < NN) h[(size_t)(n + 0) * HD + f] = a0;
        if (n + 1 < NN) h[(size_t)(n + 1) * HD + f] = a1;
        if (n + 2 < NN) h[(size_t)(n + 2) * HD + f] = a2;
        if (n + 3 < NN) h[(size_t)(n + 3) * HD + f] = a3;
    }
}

// agg[n][f] = h[n][f] * dinv[n]^2   (self-loop init)
__global__ void k_selfinit(const float* __restrict__ h, const float* __restrict__ dinv,
                           float* __restrict__ agg) {
    int idx = blockIdx.x * blockDim.x + threadIdx.x;
    if (idx >= NN * HD) return;
    int n = idx >> 7;
    float d = dinv[n];
    agg[idx] = h[idx] * d * d;
}

// agg[dst][f] += h[src][f] * dinv[src]*dinv[dst], one thread per (edge, feature)
__global__ void k_edge_agg(const float* __restrict__ h, const float* __restrict__ dinv,
                           const int* __restrict__ src, const int* __restrict__ dst,
                           float* __restrict__ agg) {
    long long tid = (long long)blockIdx.x * blockDim.x + threadIdx.x;
    int e = (int)(tid >> 7);
    int f = (int)(tid & 127);
    if (e >= NE) return;
    int s = src[e], d = dst[e];
    float c = dinv[s] * dinv[d];
    atomicAdd(&agg[(size_t)d * HD + f], h[(size_t)s * HD + f] * c);
}

// h2[n] = sum_f relu(agg[n][f] + b1[f]) * W2[f]; one wave (64 lanes) per node,
// each lane covers f=lane and f=lane+64. Block 256 = 4 nodes.
__global__ void k_layer2(const float* __restrict__ agg, const float* __restrict__ b1,
                         const float* __restrict__ W2, float* __restrict__ h2) {
    int n = blockIdx.x * 4 + (threadIdx.x >> 6);
    int lane = threadIdx.x & 63;
    if (n >= NN) return;
    const float* a = agg + (size_t)n * HD;
    float v0 = fmaxf(a[lane] + b1[lane], 0.f) * W2[lane];
    float v1 = fmaxf(a[lane + 64] + b1[lane + 64], 0.f) * W2[lane + 64];
    float s = v0 + v1;
#pragma unroll
    for (int o = 32; o > 0; o >>= 1) s += __shfl_down(s, o, 64);
    if (lane == 0) h2[n] = s;
}

__global__ void k_init2(const float* __restrict__ h2, const float* __restrict__ dinv,
                        float* __restrict__ agg2) {
    int n = blockIdx.x * blockDim.x + threadIdx.x;
    if (n >= NN) return;
    float d = dinv[n];
    agg2[n] = h2[n] * d * d;
}

__global__ void k_edge2(const float* __restrict__ h2, const float* __restrict__ dinv,
                        const int* __restrict__ src, const int* __restrict__ dst,
                        float* __restrict__ agg2) {
    int e = blockIdx.x * blockDim.x + threadIdx.x;
    if (e >= NE) return;
    int s = src[e], d = dst[e];
    atomicAdd(&agg2[d], h2[s] * dinv[s] * dinv[d]);
}

// y_hat[batch[n]] += agg2[n] + b2
__global__ void k_final(const float* __restrict__ agg2, const float* __restrict__ b2,
                        const int* __restrict__ batch, float* __restrict__ y) {
    int n = blockIdx.x * blockDim.x + threadIdx.x;
    if (n >= NN) return;
    atomicAdd(&y[batch[n]], agg2[n] + b2[0]);
}

extern "C" void kernel_launch(void* const* d_in, const int* in_sizes, int n_in,
                              void* d_out, int out_size, void* d_ws, size_t ws_size,
                              hipStream_t stream) {
    const int*   tok   = (const int*)d_in[0];
    const float* pe    = (const float*)d_in[1];
    const int*   ei    = (const int*)d_in[2];
    const int*   vei   = (const int*)d_in[3];
    const int*   batch = (const int*)d_in[4];
    const float* embed = (const float*)d_in[5];
    const float* Wt    = (const float*)d_in[6];
    const float* bt    = (const float*)d_in[7];
    const float* W1    = (const float*)d_in[8];
    const float* b1    = (const float*)d_in[9];
    const float* W2    = (const float*)d_in[10];
    const float* b2    = (const float*)d_in[11];
    const float* Wv1   = (const float*)d_in[12];
    const float* bv1   = (const float*)d_in[13];
    const float* Wv2   = (const float*)d_in[14];
    const float* bv2   = (const float*)d_in[15];

    float* y = (float*)d_out;       // [NG]
    float* x = y + NG;              // [NN*HD], also output 1

    float* h    = (float*)d_ws;                 // [NN*HD]
    float* agg  = h    + (size_t)NN * HD;       // [NN*HD]
    float* dinv = agg  + (size_t)NN * HD;       // [NN]
    float* h2   = dinv + NN;                    // [NN]
    float* agg2 = h2   + NN;                    // [NN]

    hipMemsetAsync(y, 0, NG * sizeof(float), stream);

    k_compute_x<<<(NN * HD + 255) / 256, 256, 0, stream>>>(tok, pe, embed, Wt, bt, x);

    for (int br = 0; br < 2; ++br) {
        const int* src = br ? vei : ei;
        const int* dst = src + NE;
        const float* Wa = br ? Wv1 : W1;
        const float* ba = br ? bv1 : b1;
        const float* Wb = br ? Wv2 : W2;
        const float* bb = br ? bv2 : b2;

        hipMemsetAsync(dinv, 0, NN * sizeof(float), stream);
        k_deg<<<(NE + 255) / 256, 256, 0, stream>>>(dst, dinv);
        k_dinv<<<(NN + 255) / 256, 256, 0, stream>>>(dinv);
        k_gemm128<<<(NN + 31) / 32, 128, 0, stream>>>(x, Wa, h);
        k_selfinit<<<(NN * HD + 255) / 256, 256, 0, stream>>>(h, dinv, agg);
        k_edge_agg<<<(int)(((long long)NE * HD + 255) / 256), 256, 0, stream>>>(h, dinv, src, dst, agg);
        k_layer2<<<(NN + 3) / 4, 256, 0, stream>>>(agg, ba, Wb, h2);
        k_init2<<<(NN + 255) / 256, 256, 0, stream>>>(h2, dinv, agg2);
        k_edge2<<<(NE + 255) / 256, 256, 0, stream>>>(h2, dinv, src, dst, agg2);
        k_final<<<(NN + 255) / 256, 256, 0, stream>>>(agg2, bb, batch, y);
    }
}